// Round 6
// baseline (388.668 us; speedup 1.0000x reference)
//
#include <hip/hip_runtime.h>

// Sizes (fixed by the problem)
#define BATCH 4
#define TSEQ  2048
#define UNITS 1024
#define HEADS 8
#define DH    128
#define MROWS (BATCH*TSEQ)          // 8192
#define NCAT  (2*UNITS + DH)        // 2176

typedef short bf16x8 __attribute__((ext_vector_type(8)));
typedef short short4v __attribute__((ext_vector_type(4)));
typedef float f32x4  __attribute__((ext_vector_type(4)));

__device__ __forceinline__ short f2bf(float f){
    union { float f; unsigned u; } v; v.f = f;
    unsigned r = v.u + 0x7fff + ((v.u >> 16) & 1);
    return (short)(r >> 16);
}
__device__ __forceinline__ float redsum16(float v){
    #pragma unroll
    for (int m = 1; m < 16; m <<= 1) v += __shfl_xor(v, m);
    return v;
}
__device__ __forceinline__ void gload_lds16(const void* g, void* l){
    __builtin_amdgcn_global_load_lds(
        (const __attribute__((address_space(1))) void*)g,
        (__attribute__((address_space(3))) void*)l, 16, 0, 0);
}

// log2(e)/sqrt(128): folded into Wq so scores are in log2 domain (exp2 softmax)
#define QSCALE (0.08838834764831845f * 1.4426950408889634f)

// ---------------------------------------------------------------------------
// x -> bf16 (vectorized 8/lane)
// ---------------------------------------------------------------------------
__global__ __launch_bounds__(256) void xcast_kernel(const float* __restrict__ x,
                                                    short* __restrict__ Xbf)
{
    const int N = MROWS*UNITS/8;
    for (int i = blockIdx.x*256 + threadIdx.x; i < N; i += gridDim.x*256){
        f32x4 a = *(const f32x4*)(x + (size_t)i*8);
        f32x4 b = *(const f32x4*)(x + (size_t)i*8 + 4);
        bf16x8 o;
        o[0]=f2bf(a[0]); o[1]=f2bf(a[1]); o[2]=f2bf(a[2]); o[3]=f2bf(a[3]);
        o[4]=f2bf(b[0]); o[5]=f2bf(b[1]); o[6]=f2bf(b[2]); o[7]=f2bf(b[3]);
        *(bf16x8*)(Xbf + (size_t)i*8) = o;
    }
}

// ---------------------------------------------------------------------------
// Weight transpose via LDS 64x64 tiles (both global sides coalesced).
// ---------------------------------------------------------------------------
__global__ __launch_bounds__(256) void wtrans_kernel(
    const float* __restrict__ Wq, const float* __restrict__ Wk,
    const float* __restrict__ Wv, const float* __restrict__ Wo,
    short* __restrict__ WT, short* __restrict__ WoT)
{
    __shared__ float T_lds[64][65];
    const int tid = threadIdx.x;
    const int bid = blockIdx.x;
    if (bid < 544){
        const int nt = bid >> 4, kt = bid & 15;
        const int n0 = nt*64, k0 = kt*64;
        const float* src; int scol; float sc = 1.0f; int sstride = UNITS;
        if (n0 < UNITS){ src = Wq; scol = n0; sc = QSCALE; }
        else if (n0 < 2*UNITS){ src = Wk; scol = n0 - UNITS; }
        else { src = Wv; scol = n0 - 2*UNITS; sstride = DH; }
        const int ln = tid & 63, lk0 = tid >> 6;
        for (int kk = lk0; kk < 64; kk += 4)
            T_lds[kk][ln] = src[(size_t)(k0+kk)*sstride + scol + ln] * sc;
        __syncthreads();
        const int lk = tid & 63, ln0 = tid >> 6;
        for (int nn = ln0; nn < 64; nn += 4)
            WT[(size_t)(n0+nn)*UNITS + k0 + lk] = f2bf(T_lds[lk][nn]);
    } else {
        const int t = bid - 544;
        const int nt = t >> 1, dt = t & 1;
        const int n0 = nt*64, d0 = dt*64;
        const int ln = tid & 63, lk0 = tid >> 6;
        for (int dd = lk0; dd < 64; dd += 4)
            T_lds[dd][ln] = Wo[(size_t)(d0+dd)*UNITS + n0 + ln];
        __syncthreads();
        const int ld = tid & 63, ln0 = tid >> 6;
        for (int nn = ln0; nn < 64; nn += 4)
            WoT[(size_t)(n0+nn)*DH + d0 + ld] = f2bf(T_lds[ld][nn]);
    }
}

// ---------------------------------------------------------------------------
// QKV GEMM: X[8192,1024]bf16 @ WT^T -> scatter Q,K [B,H,T,d] (Q pre-scaled,
// log2-domain), V^T [B,d,T]. 128x128 tile, BK=32, 4 waves, 16x16x32 MFMA.
// Staging via global_load_lds width=16 into linear [128][32] LDS (m97-style).
// ---------------------------------------------------------------------------
__global__ __launch_bounds__(256) void gemm_qkv_kernel(
    const short* __restrict__ X, const short* __restrict__ WT,
    short* __restrict__ Qbf, short* __restrict__ Kbf, short* __restrict__ Vt)
{
    __shared__ short A_lds[128][32];
    __shared__ short B_lds[128][32];
    const int tid = threadIdx.x;
    const int w = tid >> 6, l = tid & 63, lg = l >> 4, lr = l & 15;
    const int wm = w >> 1, wn = w & 1;
    const int n0 = blockIdx.x * 128;
    const int m0 = blockIdx.y * 128;
    const f32x4 fzero = {0.f, 0.f, 0.f, 0.f};
    f32x4 acc[4][4];
    #pragma unroll
    for (int i = 0; i < 4; i++)
        #pragma unroll
        for (int j = 0; j < 4; j++) acc[i][j] = fzero;

    const int srow = (l >> 2);          // 0..15 within 16-row chunk
    const int scol = (l & 3) * 8;       // elem col 0/8/16/24

    for (int k0 = 0; k0 < UNITS; k0 += 32){
        #pragma unroll
        for (int i = 0; i < 2; i++){
            int row = w*32 + i*16 + srow;
            gload_lds16(X  + (size_t)(m0+row)*UNITS + k0 + scol,
                        (char*)A_lds + ((w*2 + i) << 10));
            gload_lds16(WT + (size_t)(n0+row)*UNITS + k0 + scol,
                        (char*)B_lds + ((w*2 + i) << 10));
        }
        __syncthreads();
        bf16x8 af[4], bfr[4];
        #pragma unroll
        for (int mf = 0; mf < 4; mf++)
            af[mf] = *(const bf16x8*)(&A_lds[wm*64 + mf*16 + lr][lg*8]);
        #pragma unroll
        for (int nf = 0; nf < 4; nf++)
            bfr[nf] = *(const bf16x8*)(&B_lds[wn*64 + nf*16 + lr][lg*8]);
        #pragma unroll
        for (int mf = 0; mf < 4; mf++)
            #pragma unroll
            for (int nf = 0; nf < 4; nf++)
                acc[mf][nf] = __builtin_amdgcn_mfma_f32_16x16x32_bf16(
                    af[mf], bfr[nf], acc[mf][nf], 0, 0, 0);
        __syncthreads();
    }

    #pragma unroll
    for (int mf = 0; mf < 4; mf++){
        #pragma unroll
        for (int nf = 0; nf < 4; nf++){
            #pragma unroll
            for (int r = 0; r < 4; r++){
                int gr = m0 + wm*64 + mf*16 + lg*4 + r;
                int gc = n0 + wn*64 + nf*16 + lr;
                int b = gr >> 11, t = gr & 2047;
                short v = f2bf(acc[mf][nf][r]);
                if (gc < UNITS){
                    int h = gc >> 7, dd = gc & 127;
                    Qbf[(((size_t)(b*HEADS + h))*TSEQ + t)*DH + dd] = v;
                } else if (gc < 2*UNITS){
                    int h = (gc - UNITS) >> 7, dd = gc & 127;
                    Kbf[(((size_t)(b*HEADS + h))*TSEQ + t)*DH + dd] = v;
                } else {
                    int dd = gc - 2*UNITS;
                    Vt[((size_t)b*DH + dd)*TSEQ + t] = v;
                }
            }
        }
    }
}

// ---------------------------------------------------------------------------
// Stats pass: Linv[bh][t] = 1/sum(exp2(S)). No max subtraction (|S| small).
// K double-buffered in LDS, reg-prefetch of next tile, ONE barrier per tile.
// ---------------------------------------------------------------------------
__global__ __launch_bounds__(256) void stats_kernel(
    const short* __restrict__ Qbf, const short* __restrict__ Kbf,
    float* __restrict__ Lb)
{
    __shared__ short K_lds[2][64][136];
    const int tid = threadIdx.x;
    const int w = tid >> 6, l = tid & 63, lg = l >> 4, lr = l & 15;
    const int bh = blockIdx.y;
    const int qt = 31 - blockIdx.x;          // heavy tiles first
    const int q0 = qt * 64;
    const short* Qh = Qbf + (size_t)bh*TSEQ*DH;
    const short* Kh = Kbf + (size_t)bh*TSEQ*DH;
    const f32x4 fzero = {0.f, 0.f, 0.f, 0.f};

    const int srow = tid >> 4;          // 0..15 (with +i*256 -> 64 rows)
    const int sc8  = tid & 15;          // col chunk

    const int qrow = q0 + w*16 + lr;
    bf16x8 aq[4];
    #pragma unroll
    for (int ks = 0; ks < 4; ks++)
        aq[ks] = *(const bf16x8*)(Qh + (size_t)qrow*DH + ks*32 + lg*8);

    // prologue: stage tile 0 into buf 0
    bf16x8 kreg[4];
    #pragma unroll
    for (int i = 0; i < 4; i++)
        kreg[i] = *(const bf16x8*)(Kh + (size_t)(srow + i*16)*DH + sc8*8);
    #pragma unroll
    for (int i = 0; i < 4; i++)
        *(bf16x8*)(&K_lds[0][srow + i*16][sc8*8]) = kreg[i];
    __syncthreads();

    float lrow[4] = {0.f, 0.f, 0.f, 0.f};
    const int ntile = qt + 1;
    for (int t = 0; t < ntile; t++){
        const int cur = t & 1;
        if (t + 1 < ntile){
            const size_t base = (size_t)((t+1)*64 + srow)*DH + sc8*8;
            #pragma unroll
            for (int i = 0; i < 4; i++)
                kreg[i] = *(const bf16x8*)(Kh + base + (size_t)i*16*DH);
        }
        f32x4 sacc[4];
        #pragma unroll
        for (int nf = 0; nf < 4; nf++) sacc[nf] = fzero;
        __builtin_amdgcn_s_setprio(1);
        #pragma unroll
        for (int ks = 0; ks < 4; ks++){
            #pragma unroll
            for (int nf = 0; nf < 4; nf++){
                bf16x8 kb = *(const bf16x8*)(&K_lds[cur][nf*16 + lr][ks*32 + lg*8]);
                sacc[nf] = __builtin_amdgcn_mfma_f32_16x16x32_bf16(aq[ks], kb, sacc[nf], 0,0,0);
            }
        }
        __builtin_amdgcn_s_setprio(0);
        if (t == qt){        // diagonal tile: mask kv > q (exp2(-1e30)=0)
            #pragma unroll
            for (int nf = 0; nf < 4; nf++)
                #pragma unroll
                for (int r = 0; r < 4; r++)
                    if (nf*16 + lr > w*16 + lg*4 + r) sacc[nf][r] = -1e30f;
        }
        #pragma unroll
        for (int r = 0; r < 4; r++)
            lrow[r] += (exp2f(sacc[0][r]) + exp2f(sacc[1][r]))
                     + (exp2f(sacc[2][r]) + exp2f(sacc[3][r]));
        if (t + 1 < ntile){
            #pragma unroll
            for (int i = 0; i < 4; i++)
                *(bf16x8*)(&K_lds[cur ^ 1][srow + i*16][sc8*8]) = kreg[i];
        }
        __syncthreads();
    }
    #pragma unroll
    for (int r = 0; r < 4; r++) lrow[r] = redsum16(lrow[r]);
    if (lr == 0){
        #pragma unroll
        for (int r = 0; r < 4; r++){
            int t = q0 + w*16 + lg*4 + r;
            Lb[(size_t)bh*TSEQ + t] = 1.0f / lrow[r];
        }
    }
}

// ---------------------------------------------------------------------------
// attn weights: per (b, 128q x 64kv tile). Upper tiles write zeros. Active:
// loop 8 heads; Q frags from global (regs), K dbuf in LDS (1 barrier/head,
// reg-prefetch next head). Output bounced through LDS for coalesced stores.
// ---------------------------------------------------------------------------
__global__ __launch_bounds__(256) void attn_kernel(
    const short* __restrict__ Qbf, const short* __restrict__ Kbf,
    const float* __restrict__ Lb, float* __restrict__ attn)
{
    const int tid = threadIdx.x;
    const int b = blockIdx.y;
    const int qt = blockIdx.x >> 5, kvt = blockIdx.x & 31;   // 16 x 32
    const int q0 = qt*128, k0 = kvt*64;
    float* At = attn + (size_t)b*TSEQ*TSEQ;

    if (k0 > q0 + 127){   // strictly upper: exact zeros
        const f32x4 fz = {0.f, 0.f, 0.f, 0.f};
        #pragma unroll
        for (int i = 0; i < 8; i++){
            int c = tid + i*256;
            int row = c >> 4, c4 = c & 15;
            *(f32x4*)(At + (size_t)(q0+row)*TSEQ + k0 + c4*4) = fz;
        }
        return;
    }

    __shared__ short K_lds[2][64][136];   // 34816 B; reused as f32[128][68]
    const int w = tid >> 6, l = tid & 63, lg = l >> 4, lr = l & 15;
    const int srow = tid >> 4, sc8 = tid & 15;
    const f32x4 fzero = {0.f, 0.f, 0.f, 0.f};
    const size_t bh0 = (size_t)(b*HEADS)*TSEQ*DH;

    // prologue: stage head 0's K tile into buf 0
    bf16x8 kreg[4];
    {
        const short* Kh = Kbf + bh0;
        #pragma unroll
        for (int i = 0; i < 4; i++)
            kreg[i] = *(const bf16x8*)(Kh + (size_t)(k0 + srow + i*16)*DH + sc8*8);
        #pragma unroll
        for (int i = 0; i < 4; i++)
            *(bf16x8*)(&K_lds[0][srow + i*16][sc8*8]) = kreg[i];
    }
    __syncthreads();

    f32x4 wacc[2][4];
    #pragma unroll
    for (int qf = 0; qf < 2; qf++)
        #pragma unroll
        for (int nf = 0; nf < 4; nf++) wacc[qf][nf] = fzero;

    for (int h = 0; h < HEADS; h++){
        const int cur = h & 1;
        if (h + 1 < HEADS){
            const short* Kn = Kbf + bh0 + (size_t)(h+1)*TSEQ*DH;
            #pragma unroll
            for (int i = 0; i < 4; i++)
                kreg[i] = *(const bf16x8*)(Kn + (size_t)(k0 + srow + i*16)*DH + sc8*8);
        }
        // Q fragments from global (L2-resident)
        const short* Qh = Qbf + bh0 + (size_t)h*TSEQ*DH;
        bf16x8 aq[2][4];
        #pragma unroll
        for (int qf = 0; qf < 2; qf++)
            #pragma unroll
            for (int ks = 0; ks < 4; ks++)
                aq[qf][ks] = *(const bf16x8*)(Qh + (size_t)(q0 + w*32 + qf*16 + lr)*DH + ks*32 + lg*8);

        f32x4 sacc[2][4];
        #pragma unroll
        for (int qf = 0; qf < 2; qf++)
            #pragma unroll
            for (int nf = 0; nf < 4; nf++) sacc[qf][nf] = fzero;
        __builtin_amdgcn_s_setprio(1);
        #pragma unroll
        for (int ks = 0; ks < 4; ks++){
            #pragma unroll
            for (int nf = 0; nf < 4; nf++){
                bf16x8 kb = *(const bf16x8*)(&K_lds[cur][nf*16 + lr][ks*32 + lg*8]);
                sacc[0][nf] = __builtin_amdgcn_mfma_f32_16x16x32_bf16(aq[0][ks], kb, sacc[0][nf], 0,0,0);
                sacc[1][nf] = __builtin_amdgcn_mfma_f32_16x16x32_bf16(aq[1][ks], kb, sacc[1][nf], 0,0,0);
            }
        }
        __builtin_amdgcn_s_setprio(0);

        const float* Lh = Lb + ((size_t)(b*HEADS + h))*TSEQ;
        #pragma unroll
        for (int qf = 0; qf < 2; qf++){
            f32x4 rlh = *(const f32x4*)(Lh + q0 + w*32 + qf*16 + lg*4);
            #pragma unroll
            for (int nf = 0; nf < 4; nf++){
                #pragma unroll
                for (int r = 0; r < 4; r++){
                    int row = q0 + w*32 + qf*16 + lg*4 + r;
                    int col = k0 + nf*16 + lr;
                    float v = (col <= row) ? exp2f(sacc[qf][nf][r]) * rlh[r] : 0.f;
                    wacc[qf][nf][r] += v;
                }
            }
        }
        if (h + 1 < HEADS){
            #pragma unroll
            for (int i = 0; i < 4; i++)
                *(bf16x8*)(&K_lds[cur ^ 1][srow + i*16][sc8*8]) = kreg[i];
        }
        __syncthreads();
    }

    // bounce output through LDS (f32 [128][68]) for coalesced stores
    float* ob = (float*)&K_lds[0][0][0];
    #pragma unroll
    for (int qf = 0; qf < 2; qf++)
        #pragma unroll
        for (int nf = 0; nf < 4; nf++)
            #pragma unroll
            for (int r = 0; r < 4; r++)
                ob[(w*32 + qf*16 + lg*4 + r)*68 + nf*16 + lr] = wacc[qf][nf][r] * 0.125f;
    __syncthreads();
    #pragma unroll
    for (int i = 0; i < 8; i++){
        int c = tid + i*256;
        int row = c >> 4, c4 = c & 15;
        *(f32x4*)(At + (size_t)(q0+row)*TSEQ + k0 + c4*4) =
            *(const f32x4*)(ob + row*68 + c4*4);
    }
}

// ---------------------------------------------------------------------------
// PV: Obuf[b,t,d] (f32) = attn[b,t,:] @ V[b,:,d]. Split-K (4 x 512) with
// f32 atomics; single-split tiles store directly. attn read f32 -> bf16.
// ---------------------------------------------------------------------------
__global__ __launch_bounds__(256) void pv_kernel(
    const float* __restrict__ attn, const short* __restrict__ Vt,
    float* __restrict__ Obuf)
{
    __shared__ short A_lds[64][72];
    __shared__ short V_lds[128][72];
    const int tid = threadIdx.x;
    const int w = tid >> 6, l = tid & 63, lg = l >> 4, lr = l & 15;
    const int mt = blockIdx.x;           // 0..31
    const int ks0 = blockIdx.y;          // 0..3
    const int b = blockIdx.z;
    const int m0 = mt*64;
    const int kmax = m0 + 64;            // causal: cols >= m0+64 are zero
    const int kbeg = ks0*512;
    if (kbeg >= kmax) return;
    const int kend = min(kbeg + 512, kmax);
    const int nact = (kmax + 511) >> 9;
    const float* Ab = attn + (size_t)b*TSEQ*TSEQ;
    const short* Vb = Vt + (size_t)b*DH*TSEQ;
    const f32x4 fzero = {0.f, 0.f, 0.f, 0.f};
    f32x4 acc[8];
    #pragma unroll
    for (int i = 0; i < 8; i++) acc[i] = fzero;

    for (int k0 = kbeg; k0 < kend; k0 += 64){
        #pragma unroll
        for (int i = 0; i < 4; i++){
            int c = tid + i*256;
            int row = c >> 4, c4 = c & 15;
            f32x4 av = *(const f32x4*)(Ab + (size_t)(m0+row)*TSEQ + k0 + c4*4);
            short4v o;
            o[0]=f2bf(av[0]); o[1]=f2bf(av[1]); o[2]=f2bf(av[2]); o[3]=f2bf(av[3]);
            *(short4v*)(&A_lds[row][c4*4]) = o;
        }
        #pragma unroll
        for (int i = 0; i < 4; i++){
            int c = tid + i*256;
            int row = c >> 3, c8 = c & 7;
            *(bf16x8*)(&V_lds[row][c8*8]) =
                *(const bf16x8*)(Vb + (size_t)row*TSEQ + k0 + c8*8);
        }
        __syncthreads();
        __builtin_amdgcn_s_setprio(1);
        #pragma unroll
        for (int ks = 0; ks < 2; ks++){
            bf16x8 a = *(const bf16x8*)(&A_lds[w*16 + lr][ks*32 + lg*8]);
            #pragma unroll
            for (int cg = 0; cg < 8; cg++){
                bf16x8 vb = *(const bf16x8*)(&V_lds[cg*16 + lr][ks*32 + lg*8]);
                acc[cg] = __builtin_amdgcn_mfma_f32_16x16x32_bf16(a, vb, acc[cg], 0,0,0);
            }
        }
        __builtin_amdgcn_s_setprio(0);
        __syncthreads();
    }
    #pragma unroll
    for (int cg = 0; cg < 8; cg++)
        #pragma unroll
        for (int r = 0; r < 4; r++){
            int row = m0 + w*16 + lg*4 + r, col = cg*16 + lr;
            float* p = &Obuf[((size_t)b*TSEQ + row)*DH + col];
            if (nact == 1) *p = acc[cg][r];
            else atomicAdd(p, acc[cg][r]);
        }
}

// ---------------------------------------------------------------------------
// out = Obuf[8192,128]f32 @ Wo  (WoT is [1024,128] bf16). A cvt'd on the fly.
// ---------------------------------------------------------------------------
__global__ __launch_bounds__(256) void gemm_out_kernel(
    const float* __restrict__ Ob, const short* __restrict__ WoT,
    float* __restrict__ out)
{
    __shared__ short A_lds[128][40];
    __shared__ short B_lds[128][40];
    const int tid = threadIdx.x;
    const int w = tid >> 6, l = tid & 63, lg = l >> 4, lr = l & 15;
    const int wm = w >> 1, wn = w & 1;
    const int n0 = blockIdx.x * 128;
    const int m0 = blockIdx.y * 128;
    const f32x4 fzero = {0.f, 0.f, 0.f, 0.f};
    f32x4 acc[4][4];
    #pragma unroll
    for (int i = 0; i < 4; i++)
        #pragma unroll
        for (int j = 0; j < 4; j++) acc[i][j] = fzero;

    for (int k0 = 0; k0 < DH; k0 += 32){
        #pragma unroll
        for (int i = 0; i < 2; i++){
            int c = tid + i*256;
            int row = c >> 2, c8 = c & 3;
            f32x4 a0 = *(const f32x4*)(Ob + (size_t)(m0+row)*DH + k0 + c8*8);
            f32x4 a1 = *(const f32x4*)(Ob + (size_t)(m0+row)*DH + k0 + c8*8 + 4);
            bf16x8 o;
            o[0]=f2bf(a0[0]); o[1]=f2bf(a0[1]); o[2]=f2bf(a0[2]); o[3]=f2bf(a0[3]);
            o[4]=f2bf(a1[0]); o[5]=f2bf(a1[1]); o[6]=f2bf(a1[2]); o[7]=f2bf(a1[3]);
            *(bf16x8*)(&A_lds[row][c8*8]) = o;
            *(bf16x8*)(&B_lds[row][c8*8]) =
                *(const bf16x8*)(WoT + (size_t)(n0+row)*DH + k0 + c8*8);
        }
        __syncthreads();
        bf16x8 af[4], bfr[4];
        #pragma unroll
        for (int mf = 0; mf < 4; mf++)
            af[mf] = *(const bf16x8*)(&A_lds[wm*64 + mf*16 + lr][lg*8]);
        #pragma unroll
        for (int nf = 0; nf < 4; nf++)
            bfr[nf] = *(const bf16x8*)(&B_lds[wn*64 + nf*16 + lr][lg*8]);
        #pragma unroll
        for (int mf = 0; mf < 4; mf++)
            #pragma unroll
            for (int nf = 0; nf < 4; nf++)
                acc[mf][nf] = __builtin_amdgcn_mfma_f32_16x16x32_bf16(
                    af[mf], bfr[nf], acc[mf][nf], 0, 0, 0);
        __syncthreads();
    }
    #pragma unroll
    for (int mf = 0; mf < 4; mf++)
        #pragma unroll
        for (int nf = 0; nf < 4; nf++)
            #pragma unroll
            for (int r = 0; r < 4; r++){
                int gr = m0 + wm*64 + mf*16 + lg*4 + r;
                int gc = n0 + wn*64 + nf*16 + lr;
                out[(size_t)gr*UNITS + gc] = acc[mf][nf][r];
            }
}

// ---------------------------------------------------------------------------
extern "C" void kernel_launch(void* const* d_in, const int* in_sizes, int n_in,
                              void* d_out, int out_size, void* d_ws, size_t ws_size,
                              hipStream_t stream)
{
    const float* x  = (const float*)d_in[0];
    const float* Wq = (const float*)d_in[1];
    const float* Wk = (const float*)d_in[2];
    const float* Wv = (const float*)d_in[3];
    const float* Wo = (const float*)d_in[4];
    float* out  = (float*)d_out;
    float* attn = out + (size_t)MROWS*UNITS;   // 8,388,608 floats in

    char* ws = (char*)d_ws;
    short* Xbf = (short*)(ws);                       // 16,777,216 B
    short* WT  = (short*)(ws + 16777216);            //  4,456,448
    short* Qbf = (short*)(ws + 21233664);            // 16,777,216
    short* Kbf = (short*)(ws + 38010880);            // 16,777,216
    short* Vt  = (short*)(ws + 54788096);            //  2,097,152
    float* Lb  = (float*)(ws + 57147392);            //    262,144
    short* WoT = (short*)(ws + 57409536);            //    262,144
    float* Obuf = (float*)ws;   // alias: Xbf dead after gemm_qkv (4 MB f32)

    xcast_kernel<<<2048, 256, 0, stream>>>(x, Xbf);
    wtrans_kernel<<<576, 256, 0, stream>>>(Wq, Wk, Wv, Wo, WT, WoT);
    gemm_qkv_kernel<<<dim3(NCAT/128, MROWS/128), 256, 0, stream>>>(Xbf, WT, Qbf, Kbf, Vt);
    hipMemsetAsync(Obuf, 0, (size_t)MROWS*DH*sizeof(float), stream);
    stats_kernel<<<dim3(TSEQ/64, BATCH*HEADS), 256, 0, stream>>>(Qbf, Kbf, Lb);
    attn_kernel<<<dim3(16*32, BATCH), 256, 0, stream>>>(Qbf, Kbf, Lb, attn);
    pv_kernel<<<dim3(TSEQ/64, 4, BATCH), 256, 0, stream>>>(attn, Vt, Obuf);
    gemm_out_kernel<<<dim3(UNITS/128, MROWS/128), 256, 0, stream>>>(Obuf, WoT, out);
}

// Round 7
// 376.098 us; speedup vs baseline: 1.0334x; 1.0334x over previous
//
#include <hip/hip_runtime.h>

// Sizes (fixed by the problem)
#define BATCH 4
#define TSEQ  2048
#define UNITS 1024
#define HEADS 8
#define DH    128
#define MROWS (BATCH*TSEQ)          // 8192
#define NCAT  (2*UNITS + DH)        // 2176

typedef short bf16x8 __attribute__((ext_vector_type(8)));
typedef short short4v __attribute__((ext_vector_type(4)));
typedef float f32x4  __attribute__((ext_vector_type(4)));

__device__ __forceinline__ short f2bf(float f){
    union { float f; unsigned u; } v; v.f = f;
    unsigned r = v.u + 0x7fff + ((v.u >> 16) & 1);
    return (short)(r >> 16);
}
__device__ __forceinline__ float redsum16(float v){
    #pragma unroll
    for (int m = 1; m < 16; m <<= 1) v += __shfl_xor(v, m);
    return v;
}
__device__ __forceinline__ void gload_lds16(const void* g, void* l){
    __builtin_amdgcn_global_load_lds(
        (const __attribute__((address_space(1))) void*)g,
        (__attribute__((address_space(3))) void*)l, 16, 0, 0);
}

// XOR swizzle for [64][128]-bf16 LDS tiles (256B rows): spreads the 16B slot
// across 8 positions per 8-row stripe; bijective; kills the 32-way column
// conflict without padding (keeps tile at exactly 16KB).
#define SWZB(r, cbyte) ((cbyte) ^ (((r) & 7) << 4))

// log2(e)/sqrt(128): folded into Wq so scores are in log2 domain (exp2 softmax)
#define QSCALE (0.08838834764831845f * 1.4426950408889634f)

// ---------------------------------------------------------------------------
// x -> bf16 (vectorized 8/lane)
// ---------------------------------------------------------------------------
__global__ __launch_bounds__(256) void xcast_kernel(const float* __restrict__ x,
                                                    short* __restrict__ Xbf)
{
    const int N = MROWS*UNITS/8;
    for (int i = blockIdx.x*256 + threadIdx.x; i < N; i += gridDim.x*256){
        f32x4 a = *(const f32x4*)(x + (size_t)i*8);
        f32x4 b = *(const f32x4*)(x + (size_t)i*8 + 4);
        bf16x8 o;
        o[0]=f2bf(a[0]); o[1]=f2bf(a[1]); o[2]=f2bf(a[2]); o[3]=f2bf(a[3]);
        o[4]=f2bf(b[0]); o[5]=f2bf(b[1]); o[6]=f2bf(b[2]); o[7]=f2bf(b[3]);
        *(bf16x8*)(Xbf + (size_t)i*8) = o;
    }
}

// ---------------------------------------------------------------------------
// Weight transpose via LDS 64x64 tiles (both global sides coalesced).
// ---------------------------------------------------------------------------
__global__ __launch_bounds__(256) void wtrans_kernel(
    const float* __restrict__ Wq, const float* __restrict__ Wk,
    const float* __restrict__ Wv, const float* __restrict__ Wo,
    short* __restrict__ WT, short* __restrict__ WoT)
{
    __shared__ float T_lds[64][65];
    const int tid = threadIdx.x;
    const int bid = blockIdx.x;
    if (bid < 544){
        const int nt = bid >> 4, kt = bid & 15;
        const int n0 = nt*64, k0 = kt*64;
        const float* src; int scol; float sc = 1.0f; int sstride = UNITS;
        if (n0 < UNITS){ src = Wq; scol = n0; sc = QSCALE; }
        else if (n0 < 2*UNITS){ src = Wk; scol = n0 - UNITS; }
        else { src = Wv; scol = n0 - 2*UNITS; sstride = DH; }
        const int ln = tid & 63, lk0 = tid >> 6;
        for (int kk = lk0; kk < 64; kk += 4)
            T_lds[kk][ln] = src[(size_t)(k0+kk)*sstride + scol + ln] * sc;
        __syncthreads();
        const int lk = tid & 63, ln0 = tid >> 6;
        for (int nn = ln0; nn < 64; nn += 4)
            WT[(size_t)(n0+nn)*UNITS + k0 + lk] = f2bf(T_lds[lk][nn]);
    } else {
        const int t = bid - 544;
        const int nt = t >> 1, dt = t & 1;
        const int n0 = nt*64, d0 = dt*64;
        const int ln = tid & 63, lk0 = tid >> 6;
        for (int dd = lk0; dd < 64; dd += 4)
            T_lds[dd][ln] = Wo[(size_t)(d0+dd)*UNITS + n0 + ln];
        __syncthreads();
        const int ld = tid & 63, ln0 = tid >> 6;
        for (int nn = ln0; nn < 64; nn += 4)
            WoT[(size_t)(n0+nn)*DH + d0 + ld] = f2bf(T_lds[ld][nn]);
    }
}

// ---------------------------------------------------------------------------
// QKV GEMM: X[8192,1024]bf16 @ WT^T -> scatter Q,K [B,H,T,d] (Q pre-scaled,
// log2-domain), V^T [B,d,T]. 128x128 tile, BK=32, 4 waves, 16x16x32 MFMA.
// Staging via global_load_lds width=16 into linear [128][32] LDS (m97-style).
// ---------------------------------------------------------------------------
__global__ __launch_bounds__(256) void gemm_qkv_kernel(
    const short* __restrict__ X, const short* __restrict__ WT,
    short* __restrict__ Qbf, short* __restrict__ Kbf, short* __restrict__ Vt)
{
    __shared__ short A_lds[128][32];
    __shared__ short B_lds[128][32];
    const int tid = threadIdx.x;
    const int w = tid >> 6, l = tid & 63, lg = l >> 4, lr = l & 15;
    const int wm = w >> 1, wn = w & 1;
    const int n0 = blockIdx.x * 128;
    const int m0 = blockIdx.y * 128;
    const f32x4 fzero = {0.f, 0.f, 0.f, 0.f};
    f32x4 acc[4][4];
    #pragma unroll
    for (int i = 0; i < 4; i++)
        #pragma unroll
        for (int j = 0; j < 4; j++) acc[i][j] = fzero;

    const int srow = (l >> 2);          // 0..15 within 16-row chunk
    const int scol = (l & 3) * 8;       // elem col 0/8/16/24

    for (int k0 = 0; k0 < UNITS; k0 += 32){
        #pragma unroll
        for (int i = 0; i < 2; i++){
            int row = w*32 + i*16 + srow;
            gload_lds16(X  + (size_t)(m0+row)*UNITS + k0 + scol,
                        (char*)A_lds + ((w*2 + i) << 10));
            gload_lds16(WT + (size_t)(n0+row)*UNITS + k0 + scol,
                        (char*)B_lds + ((w*2 + i) << 10));
        }
        __syncthreads();
        bf16x8 af[4], bfr[4];
        #pragma unroll
        for (int mf = 0; mf < 4; mf++)
            af[mf] = *(const bf16x8*)(&A_lds[wm*64 + mf*16 + lr][lg*8]);
        #pragma unroll
        for (int nf = 0; nf < 4; nf++)
            bfr[nf] = *(const bf16x8*)(&B_lds[wn*64 + nf*16 + lr][lg*8]);
        #pragma unroll
        for (int mf = 0; mf < 4; mf++)
            #pragma unroll
            for (int nf = 0; nf < 4; nf++)
                acc[mf][nf] = __builtin_amdgcn_mfma_f32_16x16x32_bf16(
                    af[mf], bfr[nf], acc[mf][nf], 0, 0, 0);
        __syncthreads();
    }

    #pragma unroll
    for (int mf = 0; mf < 4; mf++){
        #pragma unroll
        for (int nf = 0; nf < 4; nf++){
            #pragma unroll
            for (int r = 0; r < 4; r++){
                int gr = m0 + wm*64 + mf*16 + lg*4 + r;
                int gc = n0 + wn*64 + nf*16 + lr;
                int b = gr >> 11, t = gr & 2047;
                short v = f2bf(acc[mf][nf][r]);
                if (gc < UNITS){
                    int h = gc >> 7, dd = gc & 127;
                    Qbf[(((size_t)(b*HEADS + h))*TSEQ + t)*DH + dd] = v;
                } else if (gc < 2*UNITS){
                    int h = (gc - UNITS) >> 7, dd = gc & 127;
                    Kbf[(((size_t)(b*HEADS + h))*TSEQ + t)*DH + dd] = v;
                } else {
                    int dd = gc - 2*UNITS;
                    Vt[((size_t)b*DH + dd)*TSEQ + t] = v;
                }
            }
        }
    }
}

// ---------------------------------------------------------------------------
// Stats pass: Linv[bh][t] = 1/sum(exp2(S)). No max subtraction (|S| small).
// K dbuf in swizzled 32KB LDS, reg-prefetch next tile, ONE barrier per tile.
// ---------------------------------------------------------------------------
__global__ __launch_bounds__(256) void stats_kernel(
    const short* __restrict__ Qbf, const short* __restrict__ Kbf,
    float* __restrict__ Lb)
{
    __shared__ short K_lds[2][64][128];   // swizzled, 32768 B
    const int tid = threadIdx.x;
    const int w = tid >> 6, l = tid & 63, lg = l >> 4, lr = l & 15;
    const int bh = blockIdx.y;
    const int qt = 31 - blockIdx.x;          // heavy tiles first
    const int q0 = qt * 64;
    const short* Qh = Qbf + (size_t)bh*TSEQ*DH;
    const short* Kh = Kbf + (size_t)bh*TSEQ*DH;
    const f32x4 fzero = {0.f, 0.f, 0.f, 0.f};

    const int srow = tid >> 4;          // 0..15 (with +i*16 -> 64 rows)
    const int sc8  = tid & 15;          // 16B col chunk

    const int qrow = q0 + w*16 + lr;
    bf16x8 aq[4];
    #pragma unroll
    for (int ks = 0; ks < 4; ks++)
        aq[ks] = *(const bf16x8*)(Qh + (size_t)qrow*DH + ks*32 + lg*8);

    // prologue: stage tile 0 into buf 0
    bf16x8 kreg[4];
    #pragma unroll
    for (int i = 0; i < 4; i++)
        kreg[i] = *(const bf16x8*)(Kh + (size_t)(srow + i*16)*DH + sc8*8);
    #pragma unroll
    for (int i = 0; i < 4; i++){
        int r = srow + i*16;
        *(bf16x8*)((char*)&K_lds[0][0][0] + r*256 + SWZB(r, sc8*16)) = kreg[i];
    }
    __syncthreads();

    float lrow[4] = {0.f, 0.f, 0.f, 0.f};
    const int ntile = qt + 1;
    for (int t = 0; t < ntile; t++){
        const int cur = t & 1;
        if (t + 1 < ntile){
            const size_t base = (size_t)((t+1)*64 + srow)*DH + sc8*8;
            #pragma unroll
            for (int i = 0; i < 4; i++)
                kreg[i] = *(const bf16x8*)(Kh + base + (size_t)i*16*DH);
        }
        f32x4 sacc[4];
        #pragma unroll
        for (int nf = 0; nf < 4; nf++) sacc[nf] = fzero;
        __builtin_amdgcn_s_setprio(1);
        #pragma unroll
        for (int ks = 0; ks < 4; ks++){
            #pragma unroll
            for (int nf = 0; nf < 4; nf++){
                int r = nf*16 + lr;
                bf16x8 kb = *(const bf16x8*)((char*)&K_lds[cur][0][0]
                              + r*256 + SWZB(r, ks*64 + lg*16));
                sacc[nf] = __builtin_amdgcn_mfma_f32_16x16x32_bf16(aq[ks], kb, sacc[nf], 0,0,0);
            }
        }
        __builtin_amdgcn_s_setprio(0);
        if (t == qt){        // diagonal tile: mask kv > q (exp2(-1e30)=0)
            #pragma unroll
            for (int nf = 0; nf < 4; nf++)
                #pragma unroll
                for (int r = 0; r < 4; r++)
                    if (nf*16 + lr > w*16 + lg*4 + r) sacc[nf][r] = -1e30f;
        }
        #pragma unroll
        for (int r = 0; r < 4; r++)
            lrow[r] += (exp2f(sacc[0][r]) + exp2f(sacc[1][r]))
                     + (exp2f(sacc[2][r]) + exp2f(sacc[3][r]));
        if (t + 1 < ntile){
            #pragma unroll
            for (int i = 0; i < 4; i++){
                int r = srow + i*16;
                *(bf16x8*)((char*)&K_lds[cur ^ 1][0][0] + r*256 + SWZB(r, sc8*16)) = kreg[i];
            }
        }
        __syncthreads();
    }
    #pragma unroll
    for (int r = 0; r < 4; r++) lrow[r] = redsum16(lrow[r]);
    if (lr == 0){
        #pragma unroll
        for (int r = 0; r < 4; r++){
            int t = q0 + w*16 + lg*4 + r;
            Lb[(size_t)bh*TSEQ + t] = 1.0f / lrow[r];
        }
    }
}

// ---------------------------------------------------------------------------
// attn weights: per (b, 64q x 64kv tile). Upper tiles write zeros. Active:
// loop 8 heads; Q frags from global with next-head REG PREFETCH, K dbuf in
// swizzled 32KB LDS (1 barrier/head, reg-prefetch). Output bounced through
// LDS for coalesced f32x4 stores. 5 blocks/CU (LDS 32KB, VGPR<=102).
// ---------------------------------------------------------------------------
__global__ __launch_bounds__(256, 5) void attn_kernel(
    const short* __restrict__ Qbf, const short* __restrict__ Kbf,
    const float* __restrict__ Lb, float* __restrict__ attn)
{
    const int tid = threadIdx.x;
    const int b = blockIdx.y;
    const int qt = blockIdx.x >> 5, kvt = blockIdx.x & 31;   // 32 x 32
    const int q0 = qt*64, k0 = kvt*64;
    float* At = attn + (size_t)b*TSEQ*TSEQ;

    if (kvt > qt){   // strictly upper: exact zeros (softmax of -1e9)
        const f32x4 fz = {0.f, 0.f, 0.f, 0.f};
        #pragma unroll
        for (int i = 0; i < 4; i++){
            int c = tid + i*256;
            int row = c >> 4, c4 = c & 15;
            *(f32x4*)(At + (size_t)(q0+row)*TSEQ + k0 + c4*4) = fz;
        }
        return;
    }

    __shared__ short K_lds[2][64][128];   // swizzled, 32768 B
    const int w = tid >> 6, l = tid & 63, lg = l >> 4, lr = l & 15;
    const int srow = tid >> 4, sc8 = tid & 15;
    const f32x4 fzero = {0.f, 0.f, 0.f, 0.f};
    const size_t bh0 = (size_t)(b*HEADS)*TSEQ*DH;

    // prologue: stage head 0's K tile + load head 0's Q frags
    bf16x8 kreg[4];
    {
        const short* Kh = Kbf + bh0;
        #pragma unroll
        for (int i = 0; i < 4; i++)
            kreg[i] = *(const bf16x8*)(Kh + (size_t)(k0 + srow + i*16)*DH + sc8*8);
        #pragma unroll
        for (int i = 0; i < 4; i++){
            int r = srow + i*16;
            *(bf16x8*)((char*)&K_lds[0][0][0] + r*256 + SWZB(r, sc8*16)) = kreg[i];
        }
    }
    bf16x8 aq[4];
    #pragma unroll
    for (int ks = 0; ks < 4; ks++)
        aq[ks] = *(const bf16x8*)(Qbf + bh0 + (size_t)(q0 + w*16 + lr)*DH + ks*32 + lg*8);
    __syncthreads();

    f32x4 wacc[4];
    #pragma unroll
    for (int nf = 0; nf < 4; nf++) wacc[nf] = fzero;

    for (int h = 0; h < HEADS; h++){
        const int cur = h & 1;
        bf16x8 aqn[4];
        if (h + 1 < HEADS){
            const size_t bhn = bh0 + (size_t)(h+1)*TSEQ*DH;
            const short* Kn = Kbf + bhn;
            #pragma unroll
            for (int i = 0; i < 4; i++)
                kreg[i] = *(const bf16x8*)(Kn + (size_t)(k0 + srow + i*16)*DH + sc8*8);
            const short* Qn = Qbf + bhn;
            #pragma unroll
            for (int ks = 0; ks < 4; ks++)
                aqn[ks] = *(const bf16x8*)(Qn + (size_t)(q0 + w*16 + lr)*DH + ks*32 + lg*8);
        }

        f32x4 sacc[4];
        #pragma unroll
        for (int nf = 0; nf < 4; nf++) sacc[nf] = fzero;
        __builtin_amdgcn_s_setprio(1);
        #pragma unroll
        for (int ks = 0; ks < 4; ks++){
            #pragma unroll
            for (int nf = 0; nf < 4; nf++){
                int r = nf*16 + lr;
                bf16x8 kb = *(const bf16x8*)((char*)&K_lds[cur][0][0]
                              + r*256 + SWZB(r, ks*64 + lg*16));
                sacc[nf] = __builtin_amdgcn_mfma_f32_16x16x32_bf16(aq[ks], kb, sacc[nf], 0,0,0);
            }
        }
        __builtin_amdgcn_s_setprio(0);

        if (kvt == qt){      // diagonal tile: mask kv > q
            #pragma unroll
            for (int nf = 0; nf < 4; nf++)
                #pragma unroll
                for (int r = 0; r < 4; r++)
                    if (nf*16 + lr > w*16 + lg*4 + r) sacc[nf][r] = -1e30f;
        }
        f32x4 rlh = *(const f32x4*)(Lb + ((size_t)(b*HEADS + h))*TSEQ + q0 + w*16 + lg*4);
        #pragma unroll
        for (int nf = 0; nf < 4; nf++)
            #pragma unroll
            for (int r = 0; r < 4; r++)
                wacc[nf][r] += exp2f(sacc[nf][r]) * rlh[r];

        if (h + 1 < HEADS){
            #pragma unroll
            for (int i = 0; i < 4; i++){
                int r = srow + i*16;
                *(bf16x8*)((char*)&K_lds[cur ^ 1][0][0] + r*256 + SWZB(r, sc8*16)) = kreg[i];
            }
            #pragma unroll
            for (int ks = 0; ks < 4; ks++) aq[ks] = aqn[ks];
        }
        __syncthreads();
    }

    // bounce output through LDS (f32 [64][68]) for coalesced stores
    float* ob = (float*)&K_lds[0][0][0];
    #pragma unroll
    for (int nf = 0; nf < 4; nf++)
        #pragma unroll
        for (int r = 0; r < 4; r++)
            ob[(w*16 + lg*4 + r)*68 + nf*16 + lr] = wacc[nf][r] * 0.125f;
    __syncthreads();
    #pragma unroll
    for (int i = 0; i < 4; i++){
        int c = tid + i*256;
        int row = c >> 4, c4 = c & 15;
        *(f32x4*)(At + (size_t)(q0+row)*TSEQ + k0 + c4*4) =
            *(const f32x4*)(ob + row*68 + c4*4);
    }
}

// ---------------------------------------------------------------------------
// PV: Obuf[b,t,d] (f32) = attn[b,t,:] @ V[b,:,d]. Split-K (4 x 512) with
// f32 atomics; single-split tiles store directly. attn read f32 -> bf16.
// ---------------------------------------------------------------------------
__global__ __launch_bounds__(256) void pv_kernel(
    const float* __restrict__ attn, const short* __restrict__ Vt,
    float* __restrict__ Obuf)
{
    __shared__ short A_lds[64][72];
    __shared__ short V_lds[128][72];
    const int tid = threadIdx.x;
    const int w = tid >> 6, l = tid & 63, lg = l >> 4, lr = l & 15;
    const int mt = blockIdx.x;           // 0..31
    const int ks0 = blockIdx.y;          // 0..3
    const int b = blockIdx.z;
    const int m0 = mt*64;
    const int kmax = m0 + 64;            // causal: cols >= m0+64 are zero
    const int kbeg = ks0*512;
    if (kbeg >= kmax) return;
    const int kend = min(kbeg + 512, kmax);
    const int nact = (kmax + 511) >> 9;
    const float* Ab = attn + (size_t)b*TSEQ*TSEQ;
    const short* Vb = Vt + (size_t)b*DH*TSEQ;
    const f32x4 fzero = {0.f, 0.f, 0.f, 0.f};
    f32x4 acc[8];
    #pragma unroll
    for (int i = 0; i < 8; i++) acc[i] = fzero;

    for (int k0 = kbeg; k0 < kend; k0 += 64){
        #pragma unroll
        for (int i = 0; i < 4; i++){
            int c = tid + i*256;
            int row = c >> 4, c4 = c & 15;
            f32x4 av = *(const f32x4*)(Ab + (size_t)(m0+row)*TSEQ + k0 + c4*4);
            short4v o;
            o[0]=f2bf(av[0]); o[1]=f2bf(av[1]); o[2]=f2bf(av[2]); o[3]=f2bf(av[3]);
            *(short4v*)(&A_lds[row][c4*4]) = o;
        }
        #pragma unroll
        for (int i = 0; i < 4; i++){
            int c = tid + i*256;
            int row = c >> 3, c8 = c & 7;
            *(bf16x8*)(&V_lds[row][c8*8]) =
                *(const bf16x8*)(Vb + (size_t)row*TSEQ + k0 + c8*8);
        }
        __syncthreads();
        __builtin_amdgcn_s_setprio(1);
        #pragma unroll
        for (int ks = 0; ks < 2; ks++){
            bf16x8 a = *(const bf16x8*)(&A_lds[w*16 + lr][ks*32 + lg*8]);
            #pragma unroll
            for (int cg = 0; cg < 8; cg++){
                bf16x8 vb = *(const bf16x8*)(&V_lds[cg*16 + lr][ks*32 + lg*8]);
                acc[cg] = __builtin_amdgcn_mfma_f32_16x16x32_bf16(a, vb, acc[cg], 0,0,0);
            }
        }
        __builtin_amdgcn_s_setprio(0);
        __syncthreads();
    }
    #pragma unroll
    for (int cg = 0; cg < 8; cg++)
        #pragma unroll
        for (int r = 0; r < 4; r++){
            int row = m0 + w*16 + lg*4 + r, col = cg*16 + lr;
            float* p = &Obuf[((size_t)b*TSEQ + row)*DH + col];
            if (nact == 1) *p = acc[cg][r];
            else atomicAdd(p, acc[cg][r]);
        }
}

// ---------------------------------------------------------------------------
// out = Obuf[8192,128]f32 @ Wo  (WoT is [1024,128] bf16). A cvt'd on the fly.
// ---------------------------------------------------------------------------
__global__ __launch_bounds__(256) void gemm_out_kernel(
    const float* __restrict__ Ob, const short* __restrict__ WoT,
    float* __restrict__ out)
{
    __shared__ short A_lds[128][40];
    __shared__ short B_lds[128][40];
    const int tid = threadIdx.x;
    const int w = tid >> 6, l = tid & 63, lg = l >> 4, lr = l & 15;
    const int wm = w >> 1, wn = w & 1;
    const int n0 = blockIdx.x * 128;
    const int m0 = blockIdx.y * 128;
    const f32x4 fzero = {0.f, 0.f, 0.f, 0.f};
    f32x4 acc[4][4];
    #pragma unroll
    for (int i = 0; i < 4; i++)
        #pragma unroll
        for (int j = 0; j < 4; j++) acc[i][j] = fzero;

    for (int k0 = 0; k0 < DH; k0 += 32){
        #pragma unroll
        for (int i = 0; i < 2; i++){
            int c = tid + i*256;
            int row = c >> 2, c8 = c & 3;
            f32x4 a0 = *(const f32x4*)(Ob + (size_t)(m0+row)*DH + k0 + c8*8);
            f32x4 a1 = *(const f32x4*)(Ob + (size_t)(m0+row)*DH + k0 + c8*8 + 4);
            bf16x8 o;
            o[0]=f2bf(a0[0]); o[1]=f2bf(a0[1]); o[2]=f2bf(a0[2]); o[3]=f2bf(a0[3]);
            o[4]=f2bf(a1[0]); o[5]=f2bf(a1[1]); o[6]=f2bf(a1[2]); o[7]=f2bf(a1[3]);
            *(bf16x8*)(&A_lds[row][c8*8]) = o;
            *(bf16x8*)(&B_lds[row][c8*8]) =
                *(const bf16x8*)(WoT + (size_t)(n0+row)*DH + k0 + c8*8);
        }
        __syncthreads();
        bf16x8 af[4], bfr[4];
        #pragma unroll
        for (int mf = 0; mf < 4; mf++)
            af[mf] = *(const bf16x8*)(&A_lds[wm*64 + mf*16 + lr][lg*8]);
        #pragma unroll
        for (int nf = 0; nf < 4; nf++)
            bfr[nf] = *(const bf16x8*)(&B_lds[wn*64 + nf*16 + lr][lg*8]);
        #pragma unroll
        for (int mf = 0; mf < 4; mf++)
            #pragma unroll
            for (int nf = 0; nf < 4; nf++)
                acc[mf][nf] = __builtin_amdgcn_mfma_f32_16x16x32_bf16(
                    af[mf], bfr[nf], acc[mf][nf], 0, 0, 0);
        __syncthreads();
    }
    #pragma unroll
    for (int mf = 0; mf < 4; mf++)
        #pragma unroll
        for (int nf = 0; nf < 4; nf++)
            #pragma unroll
            for (int r = 0; r < 4; r++){
                int gr = m0 + wm*64 + mf*16 + lg*4 + r;
                int gc = n0 + wn*64 + nf*16 + lr;
                out[(size_t)gr*UNITS + gc] = acc[mf][nf][r];
            }
}

// ---------------------------------------------------------------------------
extern "C" void kernel_launch(void* const* d_in, const int* in_sizes, int n_in,
                              void* d_out, int out_size, void* d_ws, size_t ws_size,
                              hipStream_t stream)
{
    const float* x  = (const float*)d_in[0];
    const float* Wq = (const float*)d_in[1];
    const float* Wk = (const float*)d_in[2];
    const float* Wv = (const float*)d_in[3];
    const float* Wo = (const float*)d_in[4];
    float* out  = (float*)d_out;
    float* attn = out + (size_t)MROWS*UNITS;   // 8,388,608 floats in

    char* ws = (char*)d_ws;
    short* Xbf = (short*)(ws);                       // 16,777,216 B
    short* WT  = (short*)(ws + 16777216);            //  4,456,448
    short* Qbf = (short*)(ws + 21233664);            // 16,777,216
    short* Kbf = (short*)(ws + 38010880);            // 16,777,216
    short* Vt  = (short*)(ws + 54788096);            //  2,097,152
    float* Lb  = (float*)(ws + 57147392);            //    262,144
    short* WoT = (short*)(ws + 57409536);            //    262,144
    float* Obuf = (float*)ws;   // alias: Xbf dead after gemm_qkv (4 MB f32)

    xcast_kernel<<<2048, 256, 0, stream>>>(x, Xbf);
    wtrans_kernel<<<576, 256, 0, stream>>>(Wq, Wk, Wv, Wo, WT, WoT);
    gemm_qkv_kernel<<<dim3(NCAT/128, MROWS/128), 256, 0, stream>>>(Xbf, WT, Qbf, Kbf, Vt);
    hipMemsetAsync(Obuf, 0, (size_t)MROWS*DH*sizeof(float), stream);
    stats_kernel<<<dim3(TSEQ/64, BATCH*HEADS), 256, 0, stream>>>(Qbf, Kbf, Lb);
    attn_kernel<<<dim3(32*32, BATCH), 256, 0, stream>>>(Qbf, Kbf, Lb, attn);
    pv_kernel<<<dim3(TSEQ/64, 4, BATCH), 256, 0, stream>>>(attn, Vt, Obuf);
    gemm_out_kernel<<<dim3(UNITS/128, MROWS/128), 256, 0, stream>>>(Obuf, WoT, out);
}